// Round 15
// baseline (78.224 us; speedup 1.0000x reference)
//
#include <hip/hip_runtime.h>
#include <stdint.h>

#define NB    128
#define NSTEP 63
#define DT    0.00390625f
#define TSC   2.8853900817779268f   // 2*log2(e): folded into GEMM1 weights

typedef __attribute__((ext_vector_type(8))) short bf16x8;
typedef __attribute__((ext_vector_type(4))) float f32x4;

union Frag { bf16x8 v; uint32_t u[4]; };

__device__ __forceinline__ short f2bf(float f) {
    uint32_t u = __float_as_uint(f);
    u += 0x7FFF + ((u >> 16) & 1);          // round-to-nearest-even
    return (short)(u >> 16);
}

__device__ __forceinline__ uint32_t pk_bf16(float lo, float hi) {
    uint32_t r;
    asm("v_cvt_pk_bf16_f32 %0, %1, %2" : "=v"(r) : "v"(lo), "v"(hi));
    return r;
}

// u = 1/(2^y + 1) with y = 2*log2e*preact (TSC folded into GEMM1 weights).
// tanh = 1 - 2u; affine part folded into GEMM2 (W2' = -2*W2, C-in' = B2 +
// sum_h W2[h,:] via 2 init MFMAs). Builtins only (inline-asm exp broke R3).
__device__ __forceinline__ float sig_u(float y) {
    float e = __builtin_amdgcn_exp2f(y);
    return __builtin_amdgcn_rcpf(e + 1.0f);
}

// R14 (77.9 us) + CLEAN PHASE-STAGGER RETEST (s_sleep, not a reg chain):
// all blocks start symmetric and the per-step barrier keeps them so; the
// tanh TRANS burst (32 TRANS/lane-step) of every co-resident wave then
// hits the quarter-rate TRANS pipe simultaneously while VALU idles.
// R10's stagger test was confounded (reg delay chain + per-step L2 noise
// streaming -> FETCH blowup); noise is now LDS-staged (R13), so this
// retest is clean. Sleep ~0/700/1400/2100 cyc keyed to blockIdx at both
// +1 and +256 strides; SALU only, zero register pressure.
__global__ __launch_bounds__(256, 4) void sde_slp(
    const float* __restrict__ x_real, const float* __restrict__ x_imag,
    const float* __restrict__ params, const float* __restrict__ noise,
    const float* __restrict__ W1, const float* __restrict__ B1,
    const float* __restrict__ W2, const float* __restrict__ B2,
    float* __restrict__ out)
{
    __shared__ f32x4 xbuf4[2][16][16];   // [dbuf][row=net*4+dim4][traj]
    __shared__ float nl[64 * 16];        // [step][traj], row 63 = row 62

    const int tid  = threadIdx.x;
    const int lane = tid & 63;
    const int l15  = lane & 15;
    const int g    = lane >> 4;
    const int wv   = tid >> 6;          // net index 0..3

    // ---- stage noise: 1008 contiguous floats -> transposed LDS ----
    {
        const float* __restrict__ nb = noise + (size_t)(blockIdx.x * 16) * NSTEP;
        #pragma unroll
        for (int k = 0; k < 4; ++k) {
            const int idx = tid + k * 256;
            if (idx < 16 * NSTEP) {
                const int traj = (idx * 4162) >> 18;     // idx/63 (magic)
                const int s    = idx - traj * 63;
                nl[s * 16 + traj] = nb[idx];
            }
        }
    }

    // ---- GEMM1 A-frags: tile t, row=l15 -> h = 16t + l15 (within net wv),
    //      elem j -> state feature 8g + j; pre-scaled by TSC ----
    Frag w1f[4];
    #pragma unroll
    for (int t = 0; t < 4; ++t) {
        const int h = 16 * t + l15;
        #pragma unroll
        for (int j = 0; j < 8; ++j)
            w1f[t].v[j] = f2bf(TSC * W1[(wv * 38 + 1 + 8 * g + j) * 64 + h]);
    }

    // ---- GEMM2 A-frags (W2' = -2*W2): row=l15=d,
    //      elem j -> h_local = 16*(2kt+(j>>2)) + 4g + (j&3) ----
    Frag w2f[2];
    #pragma unroll
    for (int kt = 0; kt < 2; ++kt) {
        #pragma unroll
        for (int j = 0; j < 8; ++j) {
            const int hl = 16 * (2 * kt + (j >> 2)) + 4 * g + (j & 3);
            w2f[kt].v[j] = f2bf(-2.0f * W2[(wv * 64 + hl) * 16 + l15]);
        }
    }

    // ---- bias + t-coefficient at C-layout positions (scaled by TSC) ----
    float pr[5];
    #pragma unroll
    for (int p = 0; p < 5; ++p) pr[p] = params[p];
    f32x4 biascur[4], wtdt[4];
    #pragma unroll
    for (int t = 0; t < 4; ++t) {
        #pragma unroll
        for (int r = 0; r < 4; ++r) {
            const int h = 16 * t + 4 * g + r;
            float b = B1[wv * 64 + h];
            #pragma unroll
            for (int p = 0; p < 5; ++p)
                b = fmaf(pr[p], W1[(wv * 38 + 33 + p) * 64 + h], b);
            biascur[t][r] = TSC * b;
            wtdt[t][r]    = (TSC * DT) * W1[(wv * 38 + 0) * 64 + h];
        }
    }

    // ---- GEMM2 C-in': B2 + sum_h W2[h, d] via 2 MFMAs with B-frag -0.5 ----
    f32x4 bc;
    #pragma unroll
    for (int r = 0; r < 4; ++r) bc[r] = B2[wv * 16 + 4 * g + r];
    {
        Frag nh;
        nh.u[0] = 0xBF00BF00u;  nh.u[1] = 0xBF00BF00u;   // bf16 -0.5 x2
        nh.u[2] = 0xBF00BF00u;  nh.u[3] = 0xBF00BF00u;
        bc = __builtin_amdgcn_mfma_f32_16x16x32_bf16(w2f[0].v, nh.v, bc, 0, 0, 0);
        bc = __builtin_amdgcn_mfma_f32_16x16x32_bf16(w2f[1].v, nh.v, bc, 0, 0, 0);
    }

    // ---- state: lane holds comps 8g..8g+7 of traj n (replicated across waves) ----
    const int n    = blockIdx.x * 16 + l15;
    const int xrow = n & (NB - 1);
    const float* __restrict__ xsrc = (g < 2) ? x_real : x_imag;
    const int xoff = (g & 1) * 8;
    f32x4 stlo = *reinterpret_cast<const f32x4*>(&xsrc[xrow * 16 + xoff]);
    f32x4 sthi = *reinterpret_cast<const f32x4*>(&xsrc[xrow * 16 + xoff + 4]);

    __syncthreads();                    // noise staging visible
    if (tid < 16) nl[63 * 16 + tid] = nl[62 * 16 + tid];

    // ---- PHASE STAGGER: ~700 cyc per unit, phase 0..3 (SALU, no regs) ----
    {
        const int phase = ((blockIdx.x >> 8) + blockIdx.x) & 3;
        for (int i = 0; i < phase; ++i)
            __builtin_amdgcn_s_sleep(11);   // ~704 cycles each
    }
    __syncthreads();                    // row-63 fill visible

    float dw = nl[l15];                 // step 0

    // exchange rows: write wv*4+g; read net*4 + 2*(g&1) (+1), nets g>>1, 2+(g>>1)
    const int wrow  = wv * 4 + g;
    const int r_dr  = (g >> 1) * 4 + 2 * (g & 1);
    const int r_df  = (2 + (g >> 1)) * 4 + 2 * (g & 1);

    for (int s = 0; s < NSTEP; ++s) {
        const float dwn = nl[(s + 1) * 16 + l15];   // row 63 = row 62 copy

        // state -> bf16 B-fragment (k-slot 8g+j = component 8g+j)
        Frag bx;
        bx.u[0] = pk_bf16(stlo[0], stlo[1]);
        bx.u[1] = pk_bf16(stlo[2], stlo[3]);
        bx.u[2] = pk_bf16(sthi[0], sthi[1]);
        bx.u[3] = pk_bf16(sthi[2], sthi[3]);

        // GEMM1: 4 MFMAs, C-in = scaled bias + t*w_t
        f32x4 acc[4];
        #pragma unroll
        for (int t = 0; t < 4; ++t)
            acc[t] = __builtin_amdgcn_mfma_f32_16x16x32_bf16(
                w1f[t].v, bx.v, biascur[t], 0, 0, 0);
        #pragma unroll
        for (int t = 0; t < 4; ++t) biascur[t] += wtdt[t];

        // GEMM2: u-activation (exp+add+rcp), K=64 over own net
        f32x4 o = bc;
        #pragma unroll
        for (int kt = 0; kt < 2; ++kt) {
            const float u0 = sig_u(acc[2 * kt][0]);
            const float u1 = sig_u(acc[2 * kt][1]);
            const float u2 = sig_u(acc[2 * kt][2]);
            const float u3 = sig_u(acc[2 * kt][3]);
            const float u4 = sig_u(acc[2 * kt + 1][0]);
            const float u5 = sig_u(acc[2 * kt + 1][1]);
            const float u6 = sig_u(acc[2 * kt + 1][2]);
            const float u7 = sig_u(acc[2 * kt + 1][3]);
            Frag pb;
            pb.u[0] = pk_bf16(u0, u1);  pb.u[1] = pk_bf16(u2, u3);
            pb.u[2] = pk_bf16(u4, u5);  pb.u[3] = pk_bf16(u6, u7);
            o = __builtin_amdgcn_mfma_f32_16x16x32_bf16(w2f[kt].v, pb.v, o, 0, 0, 0);
        }

        // ---- exchange: conflict-free consecutive-lane layout ----
        const int db = s & 1;
        xbuf4[db][wrow][l15] = o;
        __syncthreads();
        const f32x4 dr0 = xbuf4[db][r_dr][l15];
        const f32x4 dr1 = xbuf4[db][r_dr + 1][l15];
        const f32x4 df0 = xbuf4[db][r_df][l15];
        const f32x4 df1 = xbuf4[db][r_df + 1][l15];

        // Euler-Maruyama, packed v_pk_fma
        const f32x4 dt4 = (f32x4)DT;
        const f32x4 dw4 = (f32x4)dw;
        stlo = __builtin_elementwise_fma(dt4, dr0,
               __builtin_elementwise_fma(dw4, df0, stlo));
        sthi = __builtin_elementwise_fma(dt4, dr1,
               __builtin_elementwise_fma(dw4, df1, sthi));
        dw = dwn;
    }

    // ---- write out (wave 0 only): lane holds comps 8g..8g+7 of traj n ----
    if (wv == 0) {
        float4* op = reinterpret_cast<float4*>(out + (size_t)n * 32 + 8 * g);
        op[0] = make_float4(stlo[0], stlo[1], stlo[2], stlo[3]);
        op[1] = make_float4(sthi[0], sthi[1], sthi[2], sthi[3]);
    }
}

extern "C" void kernel_launch(void* const* d_in, const int* in_sizes, int n_in,
                              void* d_out, int out_size, void* d_ws, size_t ws_size,
                              hipStream_t stream) {
    const float* x_real = (const float*)d_in[0];
    const float* x_imag = (const float*)d_in[1];
    const float* params = (const float*)d_in[2];
    const float* noise  = (const float*)d_in[3];
    const float* W1     = (const float*)d_in[4];
    const float* B1     = (const float*)d_in[5];
    const float* W2     = (const float*)d_in[6];
    const float* B2     = (const float*)d_in[7];
    float* out = (float*)d_out;

    // 1024 blocks x 256 threads: 4 waves/block, one 16-traj group per block
    sde_slp<<<dim3(1024), dim3(256), 0, stream>>>(
        x_real, x_imag, params, noise, W1, B1, W2, B2, out);
}